// Round 19
// baseline (280.729 us; speedup 1.0000x reference)
//
#include <hip/hip_runtime.h>
#include <hip/hip_cooperative_groups.h>

namespace cg = cooperative_groups;

// Problem constants
#define V_SZ 32000
#define E_SZ 128
#define H_SZ 32
#define L_SZ 64
#define B_SZ 32
#define M_TOT 2048   // L*B rows
#define K2 64        // 2H
#define NVT 125      // V/256 col-slices
#define GRID_F 750   // 125 xcol x 6 sub-blocks; 3 blocks/CU guaranteed

typedef __bf16 bf16x8 __attribute__((ext_vector_type(8)));
typedef float f32x4 __attribute__((ext_vector_type(4)));

__device__ __forceinline__ unsigned short f2bf(float f) {
    unsigned int u = __float_as_uint(f);
    u += 0x7FFFu + ((u >> 16) & 1u);   // round-to-nearest-even
    return (unsigned short)(u >> 16);
}

// ---------------------------------------------------------------------------
// Swapped-operand fragments (R12-R15 proven): vocab-as-M, hcat-rows-as-N.
// D: vocab = vbase + i*16 + lg*4 + reg, hrow = rowbase + j*16 + lr
// -> each lane's reg quad = 4 consecutive vocab of one output row.
// ---------------------------------------------------------------------------
__device__ __forceinline__ void load_vfrag(
    const __bf16* __restrict__ h2oT, int vbase, int lg, int lr,
    bf16x8 vf[4][2]) {
#pragma unroll
    for (int i = 0; i < 4; ++i) {
        const __bf16* vp = h2oT + (size_t)(vbase + i * 16 + lr) * K2 + lg * 8;
        vf[i][0] = *(const bf16x8*)(vp);
        vf[i][1] = *(const bf16x8*)(vp + 32);
    }
}

__device__ __forceinline__ void load_hfrag(
    const __bf16* __restrict__ hcat, int rowbase, int lg, int lr,
    bf16x8 hf[4][2]) {
#pragma unroll
    for (int j = 0; j < 4; ++j) {
        const __bf16* hp = hcat + (size_t)(rowbase + j * 16 + lr) * K2 + lg * 8;
        hf[j][0] = *(const bf16x8*)(hp);
        hf[j][1] = *(const bf16x8*)(hp + 32);
    }
}

// Runtime-length rolling double-buffered sweep (R13/R14-proven pipeline;
// buffers statically indexed inside the parity branches).
template <typename EP>
__device__ __forceinline__ void sweepN(
    const __bf16* __restrict__ hcat, int y0, int ntiles, int lg, int lr,
    EP&& ep) {
    bf16x8 hfA[4][2], hfB[4][2];
    load_hfrag(hcat, y0, lg, lr, hfA);
    if (ntiles > 1) load_hfrag(hcat, y0 + 64, lg, lr, hfB);
    for (int t = 0; t < ntiles; ++t) {
        if (t & 1) {
            if (t + 1 < ntiles) load_hfrag(hcat, y0 + (t + 1) * 64, lg, lr, hfA);
            ep(hfB, y0 + t * 64);
        } else {
            if (t + 1 < ntiles) load_hfrag(hcat, y0 + (t + 1) * 64, lg, lr, hfB);
            ep(hfA, y0 + t * 64);
        }
    }
}

// Phase-A epilogue, register-lean: per j, one column of 8 MFMAs (4 live
// f32x4 accumulators), exp-sum, 2-shfl reduce, atomicAdd into S[row].
struct EpA {
    const bf16x8 (*vf)[2];
    float* S;
    int lane;
    __device__ __forceinline__ void operator()(const bf16x8 hf[4][2], int rowbase) const {
#pragma unroll
        for (int j = 0; j < 4; ++j) {
            f32x4 a[4];
#pragma unroll
            for (int i = 0; i < 4; ++i) {
                a[i] = (f32x4){0.f, 0.f, 0.f, 0.f};
                a[i] = __builtin_amdgcn_mfma_f32_16x16x32_bf16(vf[i][0], hf[j][0], a[i], 0, 0, 0);
                a[i] = __builtin_amdgcn_mfma_f32_16x16x32_bf16(vf[i][1], hf[j][1], a[i], 0, 0, 0);
            }
            float s = 0.f;
#pragma unroll
            for (int i = 0; i < 4; ++i)
#pragma unroll
                for (int r = 0; r < 4; ++r) s += __expf(a[i][r]);
            s += __shfl_xor(s, 16, 64);
            s += __shfl_xor(s, 32, 64);
            if (lane < 16)
                atomicAdd(&S[rowbase + j * 16 + lane], s);
        }
    }
};

// Phase-B epilogue, register-lean: per i, one row-group of 8 MFMAs (4 live
// f32x4 accumulators) then 4 direct f32x4 stores.
struct EpB {
    const bf16x8 (*vf)[2];
    const float* S;
    float* out;
    int vbase, lg, lr;
    __device__ __forceinline__ void operator()(const bf16x8 hf[4][2], int rowbase) const {
        float lsev[4];
#pragma unroll
        for (int j = 0; j < 4; ++j)
            lsev[j] = logf(S[rowbase + j * 16 + lr]);
#pragma unroll
        for (int i = 0; i < 4; ++i) {
            f32x4 a[4];
#pragma unroll
            for (int j = 0; j < 4; ++j) {
                a[j] = (f32x4){0.f, 0.f, 0.f, 0.f};
                a[j] = __builtin_amdgcn_mfma_f32_16x16x32_bf16(vf[i][0], hf[j][0], a[j], 0, 0, 0);
                a[j] = __builtin_amdgcn_mfma_f32_16x16x32_bf16(vf[i][1], hf[j][1], a[j], 0, 0, 0);
            }
#pragma unroll
            for (int j = 0; j < 4; ++j) {
                float* rp = out + (size_t)(rowbase + j * 16 + lr) * V_SZ
                          + vbase + lg * 4 + i * 16;
                f32x4 v;
                v.x = a[j].x - lsev[j];
                v.y = a[j].y - lsev[j];
                v.z = a[j].z - lsev[j];
                v.w = a[j].w - lsev[j];
                *(f32x4*)rp = v;
            }
        }
    }
};

// ---------------------------------------------------------------------------
// Kernel 1: blocks 0..499  -> transpose+convert h2o -> h2oT (64 rows each);
//           block 0 also zeroes S.  blocks 500..531 -> emb-GEMM + RNN.
// (R15-proven; kept SEPARATE so its 16 KB LDS never rides in the GEMM kernel)
// ---------------------------------------------------------------------------
__global__ __launch_bounds__(256) void k_prep_rnn(
    const int* __restrict__ inp, const float* __restrict__ we,
    const float* __restrict__ i2h1, const float* __restrict__ i2h2,
    const float* __restrict__ h2o, const float* __restrict__ bias,
    const float* __restrict__ hinit,
    unsigned short* __restrict__ hcat_u, unsigned short* __restrict__ h2oT_u,
    float* __restrict__ S) {
    const int tid = threadIdx.x;
    const int p = blockIdx.x;
    if (p < 500) {
        if (p == 0) {
#pragma unroll
            for (int i = tid; i < M_TOT; i += 256) S[i] = 0.f;
        }
        const int v = p * 64 + (tid & 63);         // [0,32000) exact
        const int kg = tid >> 6;                   // 0..3
        unsigned int* dst = (unsigned int*)(h2oT_u + (size_t)v * K2 + kg * 16);
#pragma unroll
        for (int kk = 0; kk < 16; kk += 2) {
            const int k = kg * 16 + kk;
            float a = h2o[(size_t)k * V_SZ + v];
            float b = h2o[(size_t)(k + 1) * V_SZ + v];
            dst[kk >> 1] = (unsigned int)f2bf(a) | ((unsigned int)f2bf(b) << 16);
        }
        return;
    }
    // ---- emb + RNN block (one direction, 2 batch rows) ----
    const int w2 = p - 500;                        // 0..31
    const int dir = w2 >> 4;
    const int bpair = w2 & 15;
    const float* W = dir ? i2h2 : i2h1;
    __shared__ float Xl[L_SZ * 2 * H_SZ];          // 16 KB: X[t][bb][j]
    {
        const int j = tid & 31, bb = (tid >> 5) & 1, to = tid >> 6;
        const int b = bpair * 2 + bb;
        const float bj = bias[j];
        for (int tt = 0; tt < 16; ++tt) {
            const int t = to * 16 + tt;
            const int idx = inp[t * B_SZ + b];
            const float* er = we + (size_t)idx * E_SZ;
            float acc = bj;
#pragma unroll
            for (int k0 = 0; k0 < E_SZ; k0 += 4) {
                f32x4 e4 = *(const f32x4*)(er + k0);
                acc += e4.x * W[(k0 + 0) * H_SZ + j];
                acc += e4.y * W[(k0 + 1) * H_SZ + j];
                acc += e4.z * W[(k0 + 2) * H_SZ + j];
                acc += e4.w * W[(k0 + 3) * H_SZ + j];
            }
            Xl[(t * 2 + bb) * H_SZ + j] = acc;
        }
    }
    __syncthreads();
    if (tid < 64) {
        const int lane = tid;
        const int bb = lane >> 5;
        const int b = bpair * 2 + bb;
        const int j = lane & 31;
        const int srcbase = lane & 32;
        float wh[H_SZ];
#pragma unroll
        for (int k = 0; k < H_SZ; ++k) wh[k] = W[(E_SZ + k) * H_SZ + j];
        float h = hinit[j];
        for (int step = 0; step < L_SZ; ++step) {
            const int tt = dir ? (L_SZ - 1 - step) : step;
            hcat_u[(tt * B_SZ + b) * K2 + dir * H_SZ + j] = f2bf(h);
            float a0 = Xl[(tt * 2 + bb) * H_SZ + j];
            float a1 = 0.f, a2 = 0.f, a3 = 0.f;
#pragma unroll
            for (int k = 0; k < H_SZ; k += 4) {
                a0 += __shfl(h, srcbase | k, 64) * wh[k];
                a1 += __shfl(h, srcbase | (k + 1), 64) * wh[k + 1];
                a2 += __shfl(h, srcbase | (k + 2), 64) * wh[k + 2];
                a3 += __shfl(h, srcbase | (k + 3), 64) * wh[k + 3];
            }
            float x2 = (a0 + a1) + (a2 + a3);
            float e = __expf(2.f * x2);            // tanh = 1 - 2/(e^{2x}+1)
            h = 1.f - 2.f * __builtin_amdgcn_rcpf(e + 1.f);
        }
    }
}

// ---------------------------------------------------------------------------
// Fused cooperative kernel, grid EXACTLY 750 (3 blocks/CU guaranteed by
// __launch_bounds__(256,3)): block b -> xcol = b/6, sub = b%6 owning 5-6
// row-tiles ({6,6,5,5,5,5} partition of 32). Phase A (sum-exp + atomic S)
// -> grid.sync -> phase B (recompute + store). No occupancy API anywhere.
// ---------------------------------------------------------------------------
__global__ __launch_bounds__(256, 3) void k_fused(
    const unsigned short* __restrict__ hcat_u,
    const unsigned short* __restrict__ h2oT_u,
    float* __restrict__ S, float* __restrict__ out) {
    cg::grid_group gg = cg::this_grid();
    const int tid = threadIdx.x;
    const int wave = tid >> 6, lane = tid & 63;
    const int lg = lane >> 4, lr = lane & 15;
    const int b = blockIdx.x;                      // 0..749
    const int xcol = b / 6;
    const int sub = b - xcol * 6;
    const int tstart = (sub < 2) ? sub * 6 : 12 + (sub - 2) * 5;
    const int ntiles = (sub < 2) ? 6 : 5;
    const int y0 = tstart * 64;
    const int vbase = xcol * 256 + wave * 64;
    const __bf16* hcat = (const __bf16*)hcat_u;
    const __bf16* h2oT = (const __bf16*)h2oT_u;

    bf16x8 vf[4][2];
    load_vfrag(h2oT, vbase, lg, lr, vf);

    EpA epa{vf, S, lane};
    sweepN(hcat, y0, ntiles, lg, lr, epa);

    __threadfence();
    gg.sync();

    EpB epb{vf, S, out, vbase, lg, lr};
    sweepN(hcat, y0, ntiles, lg, lr, epb);
}

// ---------------------------------------------------------------------------
// Fallback split kernels (same lean epilogues, R14-proven geometry)
// ---------------------------------------------------------------------------
__global__ __launch_bounds__(256) void k_pass_a(
    const __bf16* __restrict__ hcat, const __bf16* __restrict__ h2oT,
    float* __restrict__ S) {
    const int tid = threadIdx.x;
    const int wave = tid >> 6, lane = tid & 63;
    const int lg = lane >> 4, lr = lane & 15;
    const int y0 = blockIdx.y * 256;
    const int vbase = blockIdx.x * 256 + wave * 64;
    bf16x8 vf[4][2];
    load_vfrag(h2oT, vbase, lg, lr, vf);
    EpA epa{vf, S, lane};
    sweepN(hcat, y0, 4, lg, lr, epa);
}

__global__ __launch_bounds__(256) void k_pass_b(
    const __bf16* __restrict__ hcat, const __bf16* __restrict__ h2oT,
    const float* __restrict__ S, float* __restrict__ out) {
    const int tid = threadIdx.x;
    const int wave = tid >> 6, lane = tid & 63;
    const int lg = lane >> 4, lr = lane & 15;
    const int y0 = blockIdx.y * 256;
    const int vbase = blockIdx.x * 256 + wave * 64;
    bf16x8 vf[4][2];
    load_vfrag(h2oT, vbase, lg, lr, vf);
    EpB epb{vf, S, out, vbase, lg, lr};
    sweepN(hcat, y0, 4, lg, lr, epb);
}

// ---------------------------------------------------------------------------
extern "C" void kernel_launch(void* const* d_in, const int* in_sizes, int n_in,
                              void* d_out, int out_size, void* d_ws, size_t ws_size,
                              hipStream_t stream) {
    (void)in_sizes; (void)n_in; (void)out_size; (void)ws_size;
    const int*   inp   = (const int*)d_in[0];
    const float* we    = (const float*)d_in[1];
    const float* i2h1  = (const float*)d_in[2];
    const float* i2h2  = (const float*)d_in[3];
    const float* h2o   = (const float*)d_in[4];
    const float* bias  = (const float*)d_in[5];
    const float* hinit = (const float*)d_in[6];
    float* out = (float*)d_out;
    char* ws = (char*)d_ws;
    unsigned short* hcat_u = (unsigned short*)(ws);           //  262144 B
    unsigned short* h2oT_u = (unsigned short*)(ws + 262144);  // 4096000 B
    float*          S      = (float*)(ws + 4358144);          //    8192 B

    k_prep_rnn<<<532, 256, 0, stream>>>(inp, we, i2h1, i2h2, h2o, bias, hinit,
                                        hcat_u, h2oT_u, S);

    void* args[] = {(void*)&hcat_u, (void*)&h2oT_u, (void*)&S, (void*)&out};
    hipError_t e = hipLaunchCooperativeKernel((void*)k_fused, dim3(GRID_F),
                                              dim3(256), args, 0, stream);
    if (e != hipSuccess) {
        k_pass_a<<<dim3(NVT, 8), 256, 0, stream>>>(
            (const __bf16*)hcat_u, (const __bf16*)h2oT_u, S);
        k_pass_b<<<dim3(NVT, 8), 256, 0, stream>>>(
            (const __bf16*)hcat_u, (const __bf16*)h2oT_u, S, out);
    }
}

// Round 20
// 272.527 us; speedup vs baseline: 1.0301x; 1.0301x over previous
//
#include <hip/hip_runtime.h>
#include <hip/hip_cooperative_groups.h>

namespace cg = cooperative_groups;

// Problem constants
#define V_SZ 32000
#define E_SZ 128
#define H_SZ 32
#define L_SZ 64
#define B_SZ 32
#define M_TOT 2048   // L*B rows
#define K2 64        // 2H
#define NVT 125      // V/256 col-slices
#define GRID_F 750   // 125 xcol x 6 sub-blocks; 3 blocks/CU via launch_bounds

typedef __bf16 bf16x8 __attribute__((ext_vector_type(8)));
typedef float f32x4 __attribute__((ext_vector_type(4)));

__device__ __forceinline__ unsigned short f2bf(float f) {
    unsigned int u = __float_as_uint(f);
    u += 0x7FFFu + ((u >> 16) & 1u);   // round-to-nearest-even
    return (unsigned short)(u >> 16);
}

// ---------------------------------------------------------------------------
// Swapped-operand fragments (R12-R15 proven): vocab-as-M, hcat-rows-as-N.
// D: vocab = vbase + i*16 + lg*4 + reg, hrow = rowbase + j*16 + lr
// -> each lane's reg quad = 4 consecutive vocab of one output row.
// ---------------------------------------------------------------------------
__device__ __forceinline__ void load_vfrag(
    const __bf16* __restrict__ h2oT, int vbase, int lg, int lr,
    bf16x8 vf[4][2]) {
#pragma unroll
    for (int i = 0; i < 4; ++i) {
        const __bf16* vp = h2oT + (size_t)(vbase + i * 16 + lr) * K2 + lg * 8;
        vf[i][0] = *(const bf16x8*)(vp);
        vf[i][1] = *(const bf16x8*)(vp + 32);
    }
}

__device__ __forceinline__ void load_hfrag(
    const __bf16* __restrict__ hcat, int rowbase, int lg, int lr,
    bf16x8 hf[4][2]) {
#pragma unroll
    for (int j = 0; j < 4; ++j) {
        const __bf16* hp = hcat + (size_t)(rowbase + j * 16 + lr) * K2 + lg * 8;
        hf[j][0] = *(const bf16x8*)(hp);
        hf[j][1] = *(const bf16x8*)(hp + 32);
    }
}

// Full-ILP tile GEMM (R15-proven): 16 independent accumulators, 32 MFMAs.
__device__ __forceinline__ void tile_gemm_t(
    const bf16x8 vf[4][2], const bf16x8 hf[4][2], f32x4 acc[4][4]) {
#pragma unroll
    for (int i = 0; i < 4; ++i)
#pragma unroll
        for (int j = 0; j < 4; ++j) acc[i][j] = (f32x4){0.f, 0.f, 0.f, 0.f};
#pragma unroll
    for (int i = 0; i < 4; ++i)
#pragma unroll
        for (int j = 0; j < 4; ++j) {
            acc[i][j] = __builtin_amdgcn_mfma_f32_16x16x32_bf16(vf[i][0], hf[j][0], acc[i][j], 0, 0, 0);
            acc[i][j] = __builtin_amdgcn_mfma_f32_16x16x32_bf16(vf[i][1], hf[j][1], acc[i][j], 0, 0, 0);
        }
}

// Phase-A epilogue (R15-proven, full acc): sum-exp + 2-shfl reduce + atomic.
struct EpA {
    const bf16x8 (*vf)[2];
    float* S;
    int lane;
    __device__ __forceinline__ void operator()(const bf16x8 hf[4][2], int rowbase) const {
        f32x4 acc[4][4];
        tile_gemm_t((const bf16x8(*)[2])vf, hf, acc);
        float srow[4];
#pragma unroll
        for (int j = 0; j < 4; ++j) {
            float s = 0.f;
#pragma unroll
            for (int i = 0; i < 4; ++i)
#pragma unroll
                for (int r = 0; r < 4; ++r) s += __expf(acc[i][j][r]);
            srow[j] = s;
        }
#pragma unroll
        for (int j = 0; j < 4; ++j) {
            srow[j] += __shfl_xor(srow[j], 16, 64);
            srow[j] += __shfl_xor(srow[j], 32, 64);
        }
        if (lane < 16) {
#pragma unroll
            for (int j = 0; j < 4; ++j)
                atomicAdd(&S[rowbase + j * 16 + lane], srow[j]);
        }
    }
};

// Phase-B epilogue (R15-proven, full acc): lse from S, direct f32x4 stores.
struct EpB {
    const bf16x8 (*vf)[2];
    const float* S;
    float* out;
    int vbase, lg, lr;
    __device__ __forceinline__ void operator()(const bf16x8 hf[4][2], int rowbase) const {
        float lsev[4];
#pragma unroll
        for (int j = 0; j < 4; ++j)
            lsev[j] = logf(S[rowbase + j * 16 + lr]);
        f32x4 acc[4][4];
        tile_gemm_t((const bf16x8(*)[2])vf, hf, acc);
#pragma unroll
        for (int j = 0; j < 4; ++j) {
            float* rp = out + (size_t)(rowbase + j * 16 + lr) * V_SZ + vbase + lg * 4;
#pragma unroll
            for (int i = 0; i < 4; ++i) {
                f32x4 v;
                v.x = acc[i][j].x - lsev[j];
                v.y = acc[i][j].y - lsev[j];
                v.z = acc[i][j].z - lsev[j];
                v.w = acc[i][j].w - lsev[j];
                *(f32x4*)(rp + i * 16) = v;
            }
        }
    }
};

// Single-buffered runtime-length sweep: at 3 blocks/CU (12 waves/CU), TLP
// replaces the intra-block prefetch; saves 32 regs so full acc fits.
template <typename EP>
__device__ __forceinline__ void sweepS(
    const __bf16* __restrict__ hcat, int y0, int ntiles, int lg, int lr,
    EP&& ep) {
    for (int t = 0; t < ntiles; ++t) {
        bf16x8 hf[4][2];
        load_hfrag(hcat, y0 + t * 64, lg, lr, hf);
        ep(hf, y0 + t * 64);
    }
}

// ---------------------------------------------------------------------------
// Kernel 1: blocks 0..499  -> transpose+convert h2o -> h2oT (64 rows each);
//           block 0 also zeroes S.  blocks 500..531 -> emb-GEMM + RNN.
// (R15-proven; SEPARATE so its 16 KB LDS never rides in the GEMM kernel)
// ---------------------------------------------------------------------------
__global__ __launch_bounds__(256) void k_prep_rnn(
    const int* __restrict__ inp, const float* __restrict__ we,
    const float* __restrict__ i2h1, const float* __restrict__ i2h2,
    const float* __restrict__ h2o, const float* __restrict__ bias,
    const float* __restrict__ hinit,
    unsigned short* __restrict__ hcat_u, unsigned short* __restrict__ h2oT_u,
    float* __restrict__ S) {
    const int tid = threadIdx.x;
    const int p = blockIdx.x;
    if (p < 500) {
        if (p == 0) {
#pragma unroll
            for (int i = tid; i < M_TOT; i += 256) S[i] = 0.f;
        }
        const int v = p * 64 + (tid & 63);         // [0,32000) exact
        const int kg = tid >> 6;                   // 0..3
        unsigned int* dst = (unsigned int*)(h2oT_u + (size_t)v * K2 + kg * 16);
#pragma unroll
        for (int kk = 0; kk < 16; kk += 2) {
            const int k = kg * 16 + kk;
            float a = h2o[(size_t)k * V_SZ + v];
            float b = h2o[(size_t)(k + 1) * V_SZ + v];
            dst[kk >> 1] = (unsigned int)f2bf(a) | ((unsigned int)f2bf(b) << 16);
        }
        return;
    }
    // ---- emb + RNN block (one direction, 2 batch rows) ----
    const int w2 = p - 500;                        // 0..31
    const int dir = w2 >> 4;
    const int bpair = w2 & 15;
    const float* W = dir ? i2h2 : i2h1;
    __shared__ float Xl[L_SZ * 2 * H_SZ];          // 16 KB: X[t][bb][j]
    {
        const int j = tid & 31, bb = (tid >> 5) & 1, to = tid >> 6;
        const int b = bpair * 2 + bb;
        const float bj = bias[j];
        for (int tt = 0; tt < 16; ++tt) {
            const int t = to * 16 + tt;
            const int idx = inp[t * B_SZ + b];
            const float* er = we + (size_t)idx * E_SZ;
            float acc = bj;
#pragma unroll
            for (int k0 = 0; k0 < E_SZ; k0 += 4) {
                f32x4 e4 = *(const f32x4*)(er + k0);
                acc += e4.x * W[(k0 + 0) * H_SZ + j];
                acc += e4.y * W[(k0 + 1) * H_SZ + j];
                acc += e4.z * W[(k0 + 2) * H_SZ + j];
                acc += e4.w * W[(k0 + 3) * H_SZ + j];
            }
            Xl[(t * 2 + bb) * H_SZ + j] = acc;
        }
    }
    __syncthreads();
    if (tid < 64) {
        const int lane = tid;
        const int bb = lane >> 5;
        const int b = bpair * 2 + bb;
        const int j = lane & 31;
        const int srcbase = lane & 32;
        float wh[H_SZ];
#pragma unroll
        for (int k = 0; k < H_SZ; ++k) wh[k] = W[(E_SZ + k) * H_SZ + j];
        float h = hinit[j];
        for (int step = 0; step < L_SZ; ++step) {
            const int tt = dir ? (L_SZ - 1 - step) : step;
            hcat_u[(tt * B_SZ + b) * K2 + dir * H_SZ + j] = f2bf(h);
            float a0 = Xl[(tt * 2 + bb) * H_SZ + j];
            float a1 = 0.f, a2 = 0.f, a3 = 0.f;
#pragma unroll
            for (int k = 0; k < H_SZ; k += 4) {
                a0 += __shfl(h, srcbase | k, 64) * wh[k];
                a1 += __shfl(h, srcbase | (k + 1), 64) * wh[k + 1];
                a2 += __shfl(h, srcbase | (k + 2), 64) * wh[k + 2];
                a3 += __shfl(h, srcbase | (k + 3), 64) * wh[k + 3];
            }
            float x2 = (a0 + a1) + (a2 + a3);
            float e = __expf(2.f * x2);            // tanh = 1 - 2/(e^{2x}+1)
            h = 1.f - 2.f * __builtin_amdgcn_rcpf(e + 1.f);
        }
    }
}

// ---------------------------------------------------------------------------
// Fused cooperative kernel, grid EXACTLY 750, 3 blocks/CU via
// __launch_bounds__(256,3). Block b -> xcol = b/6, sub = b%6 owning 5-6
// row-tiles ({6,6,5,5,5,5} partition of 32). R15's full-ILP epilogues;
// single-buffered hfrag so the full accumulator set fits in 170 regs.
// ---------------------------------------------------------------------------
__global__ __launch_bounds__(256, 3) void k_fused(
    const unsigned short* __restrict__ hcat_u,
    const unsigned short* __restrict__ h2oT_u,
    float* __restrict__ S, float* __restrict__ out) {
    cg::grid_group gg = cg::this_grid();
    const int tid = threadIdx.x;
    const int wave = tid >> 6, lane = tid & 63;
    const int lg = lane >> 4, lr = lane & 15;
    const int b = blockIdx.x;                      // 0..749
    const int xcol = b / 6;
    const int sub = b - xcol * 6;
    const int tstart = (sub < 2) ? sub * 6 : 12 + (sub - 2) * 5;
    const int ntiles = (sub < 2) ? 6 : 5;
    const int y0 = tstart * 64;
    const int vbase = xcol * 256 + wave * 64;
    const __bf16* hcat = (const __bf16*)hcat_u;
    const __bf16* h2oT = (const __bf16*)h2oT_u;

    bf16x8 vf[4][2];
    load_vfrag(h2oT, vbase, lg, lr, vf);

    EpA epa{vf, S, lane};
    sweepS(hcat, y0, ntiles, lg, lr, epa);

    __threadfence();
    gg.sync();

    EpB epb{vf, S, out, vbase, lg, lr};
    sweepS(hcat, y0, ntiles, lg, lr, epb);
}

// ---------------------------------------------------------------------------
// Fallback split kernels (R14-proven geometry, same epilogues)
// ---------------------------------------------------------------------------
__global__ __launch_bounds__(256) void k_pass_a(
    const __bf16* __restrict__ hcat, const __bf16* __restrict__ h2oT,
    float* __restrict__ S) {
    const int tid = threadIdx.x;
    const int wave = tid >> 6, lane = tid & 63;
    const int lg = lane >> 4, lr = lane & 15;
    const int y0 = blockIdx.y * 256;
    const int vbase = blockIdx.x * 256 + wave * 64;
    bf16x8 vf[4][2];
    load_vfrag(h2oT, vbase, lg, lr, vf);
    EpA epa{vf, S, lane};
    sweepS(hcat, y0, 4, lg, lr, epa);
}

__global__ __launch_bounds__(256) void k_pass_b(
    const __bf16* __restrict__ hcat, const __bf16* __restrict__ h2oT,
    const float* __restrict__ S, float* __restrict__ out) {
    const int tid = threadIdx.x;
    const int wave = tid >> 6, lane = tid & 63;
    const int lg = lane >> 4, lr = lane & 15;
    const int y0 = blockIdx.y * 256;
    const int vbase = blockIdx.x * 256 + wave * 64;
    bf16x8 vf[4][2];
    load_vfrag(h2oT, vbase, lg, lr, vf);
    EpB epb{vf, S, out, vbase, lg, lr};
    sweepS(hcat, y0, 4, lg, lr, epb);
}

// ---------------------------------------------------------------------------
extern "C" void kernel_launch(void* const* d_in, const int* in_sizes, int n_in,
                              void* d_out, int out_size, void* d_ws, size_t ws_size,
                              hipStream_t stream) {
    (void)in_sizes; (void)n_in; (void)out_size; (void)ws_size;
    const int*   inp   = (const int*)d_in[0];
    const float* we    = (const float*)d_in[1];
    const float* i2h1  = (const float*)d_in[2];
    const float* i2h2  = (const float*)d_in[3];
    const float* h2o   = (const float*)d_in[4];
    const float* bias  = (const float*)d_in[5];
    const float* hinit = (const float*)d_in[6];
    float* out = (float*)d_out;
    char* ws = (char*)d_ws;
    unsigned short* hcat_u = (unsigned short*)(ws);           //  262144 B
    unsigned short* h2oT_u = (unsigned short*)(ws + 262144);  // 4096000 B
    float*          S      = (float*)(ws + 4358144);          //    8192 B

    k_prep_rnn<<<532, 256, 0, stream>>>(inp, we, i2h1, i2h2, h2o, bias, hinit,
                                        hcat_u, h2oT_u, S);

    void* args[] = {(void*)&hcat_u, (void*)&h2oT_u, (void*)&S, (void*)&out};
    hipError_t e = hipLaunchCooperativeKernel((void*)k_fused, dim3(GRID_F),
                                              dim3(256), args, 0, stream);
    if (e != hipSuccess) {
        k_pass_a<<<dim3(NVT, 8), 256, 0, stream>>>(
            (const __bf16*)hcat_u, (const __bf16*)h2oT_u, S);
        k_pass_b<<<dim3(NVT, 8), 256, 0, stream>>>(
            (const __bf16*)hcat_u, (const __bf16*)h2oT_u, S, out);
    }
}

// Round 21
// 242.393 us; speedup vs baseline: 1.1582x; 1.1243x over previous
//
#include <hip/hip_runtime.h>
#include <hip/hip_cooperative_groups.h>

namespace cg = cooperative_groups;

// Problem constants
#define V_SZ 32000
#define E_SZ 128
#define H_SZ 32
#define L_SZ 64
#define B_SZ 32
#define M_TOT 2048   // L*B rows
#define K2 64        // 2H
#define NVT 125      // V/256 col-slices
#define NUNIT 1000   // 125 xcol x 8 ygroups (4 tiles each)
#define GRID_F 512   // hard-coded: 2 blocks/CU, always co-resident

typedef __bf16 bf16x8 __attribute__((ext_vector_type(8)));
typedef float f32x4 __attribute__((ext_vector_type(4)));

__device__ __forceinline__ unsigned short f2bf(float f) {
    unsigned int u = __float_as_uint(f);
    u += 0x7FFFu + ((u >> 16) & 1u);   // round-to-nearest-even
    return (unsigned short)(u >> 16);
}

// ---------------------------------------------------------------------------
// Swapped-operand fragments (R12-R15 proven): vocab-as-M, hcat-rows-as-N.
// D: vocab = vbase + i*16 + lg*4 + reg, hrow = rowbase + j*16 + lr
// -> each lane's reg quad = 4 consecutive vocab of one output row.
// ---------------------------------------------------------------------------
__device__ __forceinline__ void load_vfrag(
    const __bf16* __restrict__ h2oT, int vbase, int lg, int lr,
    bf16x8 vf[4][2]) {
#pragma unroll
    for (int i = 0; i < 4; ++i) {
        const __bf16* vp = h2oT + (size_t)(vbase + i * 16 + lr) * K2 + lg * 8;
        vf[i][0] = *(const bf16x8*)(vp);
        vf[i][1] = *(const bf16x8*)(vp + 32);
    }
}

__device__ __forceinline__ void load_hfrag(
    const __bf16* __restrict__ hcat, int rowbase, int lg, int lr,
    bf16x8 hf[4][2]) {
#pragma unroll
    for (int j = 0; j < 4; ++j) {
        const __bf16* hp = hcat + (size_t)(rowbase + j * 16 + lr) * K2 + lg * 8;
        hf[j][0] = *(const bf16x8*)(hp);
        hf[j][1] = *(const bf16x8*)(hp + 32);
    }
}

// Full-ILP tile GEMM (R15-proven): 16 independent accumulators, 32 MFMAs.
__device__ __forceinline__ void tile_gemm_t(
    const bf16x8 vf[4][2], const bf16x8 hf[4][2], f32x4 acc[4][4]) {
#pragma unroll
    for (int i = 0; i < 4; ++i)
#pragma unroll
        for (int j = 0; j < 4; ++j) acc[i][j] = (f32x4){0.f, 0.f, 0.f, 0.f};
#pragma unroll
    for (int i = 0; i < 4; ++i)
#pragma unroll
        for (int j = 0; j < 4; ++j) {
            acc[i][j] = __builtin_amdgcn_mfma_f32_16x16x32_bf16(vf[i][0], hf[j][0], acc[i][j], 0, 0, 0);
            acc[i][j] = __builtin_amdgcn_mfma_f32_16x16x32_bf16(vf[i][1], hf[j][1], acc[i][j], 0, 0, 0);
        }
}

// 4-tile sweep with rolling double-buffered hfrag (R13/R14-proven pipeline).
template <typename EP>
__device__ __forceinline__ void sweep4(
    const __bf16* __restrict__ hcat, int y0, int lg, int lr, EP&& ep) {
    bf16x8 hfA[4][2], hfB[4][2];
    load_hfrag(hcat, y0, lg, lr, hfA);
    load_hfrag(hcat, y0 + 64, lg, lr, hfB);
    ep(hfA, y0);
    load_hfrag(hcat, y0 + 128, lg, lr, hfA);
    ep(hfB, y0 + 64);
    load_hfrag(hcat, y0 + 192, lg, lr, hfB);
    ep(hfA, y0 + 128);
    ep(hfB, y0 + 192);
}

// Phase-A epilogue: sum-exp + shfl reduce + atomicAdd into S[row].
struct EpA {
    const bf16x8 (*vf)[2];
    float* S;
    int lane;
    __device__ __forceinline__ void operator()(const bf16x8 hf[4][2], int rowbase) const {
        f32x4 acc[4][4];
        tile_gemm_t((const bf16x8(*)[2])vf, hf, acc);
        float srow[4];
#pragma unroll
        for (int j = 0; j < 4; ++j) {
            float s = 0.f;
#pragma unroll
            for (int i = 0; i < 4; ++i)
#pragma unroll
                for (int r = 0; r < 4; ++r) s += __expf(acc[i][j][r]);
            srow[j] = s;
        }
#pragma unroll
        for (int j = 0; j < 4; ++j) {
            srow[j] += __shfl_xor(srow[j], 16, 64);
            srow[j] += __shfl_xor(srow[j], 32, 64);
        }
        if (lane < 16) {
#pragma unroll
            for (int j = 0; j < 4; ++j)
                atomicAdd(&S[rowbase + j * 16 + lane], srow[j]);
        }
    }
};

// Phase-B epilogue: lse from S, recompute, direct f32x4 stores.
struct EpB {
    const bf16x8 (*vf)[2];
    const float* S;
    float* out;
    int vbase, lg, lr;
    __device__ __forceinline__ void operator()(const bf16x8 hf[4][2], int rowbase) const {
        float lsev[4];
#pragma unroll
        for (int j = 0; j < 4; ++j)
            lsev[j] = logf(S[rowbase + j * 16 + lr]);
        f32x4 acc[4][4];
        tile_gemm_t((const bf16x8(*)[2])vf, hf, acc);
#pragma unroll
        for (int j = 0; j < 4; ++j) {
            float* rp = out + (size_t)(rowbase + j * 16 + lr) * V_SZ + vbase + lg * 4;
#pragma unroll
            for (int i = 0; i < 4; ++i) {
                f32x4 v;
                v.x = acc[i][j].x - lsev[j];
                v.y = acc[i][j].y - lsev[j];
                v.z = acc[i][j].z - lsev[j];
                v.w = acc[i][j].w - lsev[j];
                *(f32x4*)(rp + i * 16) = v;
            }
        }
    }
};

// ---------------------------------------------------------------------------
// Kernel 1: blocks 0..499  -> transpose+convert h2o -> h2oT (64 rows each);
//           block 0 also zeroes S.  blocks 500..531 -> emb-GEMM + RNN.
// (R15-proven; SEPARATE so its 16 KB LDS never rides in the GEMM kernel)
// ---------------------------------------------------------------------------
__global__ __launch_bounds__(256) void k_prep_rnn(
    const int* __restrict__ inp, const float* __restrict__ we,
    const float* __restrict__ i2h1, const float* __restrict__ i2h2,
    const float* __restrict__ h2o, const float* __restrict__ bias,
    const float* __restrict__ hinit,
    unsigned short* __restrict__ hcat_u, unsigned short* __restrict__ h2oT_u,
    float* __restrict__ S) {
    const int tid = threadIdx.x;
    const int p = blockIdx.x;
    if (p < 500) {
        if (p == 0) {
#pragma unroll
            for (int i = tid; i < M_TOT; i += 256) S[i] = 0.f;
        }
        const int v = p * 64 + (tid & 63);         // [0,32000) exact
        const int kg = tid >> 6;                   // 0..3
        unsigned int* dst = (unsigned int*)(h2oT_u + (size_t)v * K2 + kg * 16);
#pragma unroll
        for (int kk = 0; kk < 16; kk += 2) {
            const int k = kg * 16 + kk;
            float a = h2o[(size_t)k * V_SZ + v];
            float b = h2o[(size_t)(k + 1) * V_SZ + v];
            dst[kk >> 1] = (unsigned int)f2bf(a) | ((unsigned int)f2bf(b) << 16);
        }
        return;
    }
    // ---- emb + RNN block (one direction, 2 batch rows) ----
    const int w2 = p - 500;                        // 0..31
    const int dir = w2 >> 4;
    const int bpair = w2 & 15;
    const float* W = dir ? i2h2 : i2h1;
    __shared__ float Xl[L_SZ * 2 * H_SZ];          // 16 KB: X[t][bb][j]
    {
        const int j = tid & 31, bb = (tid >> 5) & 1, to = tid >> 6;
        const int b = bpair * 2 + bb;
        const float bj = bias[j];
        for (int tt = 0; tt < 16; ++tt) {
            const int t = to * 16 + tt;
            const int idx = inp[t * B_SZ + b];
            const float* er = we + (size_t)idx * E_SZ;
            float acc = bj;
#pragma unroll
            for (int k0 = 0; k0 < E_SZ; k0 += 4) {
                f32x4 e4 = *(const f32x4*)(er + k0);
                acc += e4.x * W[(k0 + 0) * H_SZ + j];
                acc += e4.y * W[(k0 + 1) * H_SZ + j];
                acc += e4.z * W[(k0 + 2) * H_SZ + j];
                acc += e4.w * W[(k0 + 3) * H_SZ + j];
            }
            Xl[(t * 2 + bb) * H_SZ + j] = acc;
        }
    }
    __syncthreads();
    if (tid < 64) {
        const int lane = tid;
        const int bb = lane >> 5;
        const int b = bpair * 2 + bb;
        const int j = lane & 31;
        const int srcbase = lane & 32;
        float wh[H_SZ];
#pragma unroll
        for (int k = 0; k < H_SZ; ++k) wh[k] = W[(E_SZ + k) * H_SZ + j];
        float h = hinit[j];
        for (int step = 0; step < L_SZ; ++step) {
            const int tt = dir ? (L_SZ - 1 - step) : step;
            hcat_u[(tt * B_SZ + b) * K2 + dir * H_SZ + j] = f2bf(h);
            float a0 = Xl[(tt * 2 + bb) * H_SZ + j];
            float a1 = 0.f, a2 = 0.f, a3 = 0.f;
#pragma unroll
            for (int k = 0; k < H_SZ; k += 4) {
                a0 += __shfl(h, srcbase | k, 64) * wh[k];
                a1 += __shfl(h, srcbase | (k + 1), 64) * wh[k + 1];
                a2 += __shfl(h, srcbase | (k + 2), 64) * wh[k + 2];
                a3 += __shfl(h, srcbase | (k + 3), 64) * wh[k + 3];
            }
            float x2 = (a0 + a1) + (a2 + a3);
            float e = __expf(2.f * x2);            // tanh = 1 - 2/(e^{2x}+1)
            h = 1.f - 2.f * __builtin_amdgcn_rcpf(e + 1.f);
        }
    }
}

// ---------------------------------------------------------------------------
// Fused cooperative kernel, grid HARD-CODED 512 (2 blocks/CU — always
// co-resident, no occupancy API). Grid-stride over 1000 units (unit = xcol
// x 4-tile ygroup): phase A (sum-exp + atomic S) -> grid.sync -> phase B
// (recompute + store). Zero LDS, natural register allocation (VGPR ~96).
// ---------------------------------------------------------------------------
__global__ __launch_bounds__(256) void k_fused(
    const unsigned short* __restrict__ hcat_u,
    const unsigned short* __restrict__ h2oT_u,
    float* __restrict__ S, float* __restrict__ out) {
    cg::grid_group gg = cg::this_grid();
    const int tid = threadIdx.x;
    const int wave = tid >> 6, lane = tid & 63;
    const int lg = lane >> 4, lr = lane & 15;
    const int g = gridDim.x;
    const __bf16* hcat = (const __bf16*)hcat_u;
    const __bf16* h2oT = (const __bf16*)h2oT_u;

    // ---- phase A ----
    for (int u = blockIdx.x; u < NUNIT; u += g) {
        const int vbase = (u >> 3) * 256 + wave * 64;
        const int y0 = (u & 7) * 256;
        bf16x8 vf[4][2];
        load_vfrag(h2oT, vbase, lg, lr, vf);
        EpA epa{vf, S, lane};
        sweep4(hcat, y0, lg, lr, epa);
    }
    __threadfence();
    gg.sync();

    // ---- phase B ----
    for (int u = blockIdx.x; u < NUNIT; u += g) {
        const int vbase = (u >> 3) * 256 + wave * 64;
        const int y0 = (u & 7) * 256;
        bf16x8 vf[4][2];
        load_vfrag(h2oT, vbase, lg, lr, vf);
        EpB epb{vf, S, out, vbase, lg, lr};
        sweep4(hcat, y0, lg, lr, epb);
    }
}

// ---------------------------------------------------------------------------
// Fallback split kernels (same epilogues, R14-proven geometry)
// ---------------------------------------------------------------------------
__global__ __launch_bounds__(256) void k_pass_a(
    const __bf16* __restrict__ hcat, const __bf16* __restrict__ h2oT,
    float* __restrict__ S) {
    const int tid = threadIdx.x;
    const int wave = tid >> 6, lane = tid & 63;
    const int lg = lane >> 4, lr = lane & 15;
    const int y0 = blockIdx.y * 256;
    const int vbase = blockIdx.x * 256 + wave * 64;
    bf16x8 vf[4][2];
    load_vfrag(h2oT, vbase, lg, lr, vf);
    EpA epa{vf, S, lane};
    sweep4(hcat, y0, lg, lr, epa);
}

__global__ __launch_bounds__(256) void k_pass_b(
    const __bf16* __restrict__ hcat, const __bf16* __restrict__ h2oT,
    const float* __restrict__ S, float* __restrict__ out) {
    const int tid = threadIdx.x;
    const int wave = tid >> 6, lane = tid & 63;
    const int lg = lane >> 4, lr = lane & 15;
    const int y0 = blockIdx.y * 256;
    const int vbase = blockIdx.x * 256 + wave * 64;
    bf16x8 vf[4][2];
    load_vfrag(h2oT, vbase, lg, lr, vf);
    EpB epb{vf, S, out, vbase, lg, lr};
    sweep4(hcat, y0, lg, lr, epb);
}

// ---------------------------------------------------------------------------
extern "C" void kernel_launch(void* const* d_in, const int* in_sizes, int n_in,
                              void* d_out, int out_size, void* d_ws, size_t ws_size,
                              hipStream_t stream) {
    (void)in_sizes; (void)n_in; (void)out_size; (void)ws_size;
    const int*   inp   = (const int*)d_in[0];
    const float* we    = (const float*)d_in[1];
    const float* i2h1  = (const float*)d_in[2];
    const float* i2h2  = (const float*)d_in[3];
    const float* h2o   = (const float*)d_in[4];
    const float* bias  = (const float*)d_in[5];
    const float* hinit = (const float*)d_in[6];
    float* out = (float*)d_out;
    char* ws = (char*)d_ws;
    unsigned short* hcat_u = (unsigned short*)(ws);           //  262144 B
    unsigned short* h2oT_u = (unsigned short*)(ws + 262144);  // 4096000 B
    float*          S      = (float*)(ws + 4358144);          //    8192 B

    k_prep_rnn<<<532, 256, 0, stream>>>(inp, we, i2h1, i2h2, h2o, bias, hinit,
                                        hcat_u, h2oT_u, S);

    void* args[] = {(void*)&hcat_u, (void*)&h2oT_u, (void*)&S, (void*)&out};
    hipError_t e = hipLaunchCooperativeKernel((void*)k_fused, dim3(GRID_F),
                                              dim3(256), args, 0, stream);
    if (e != hipSuccess) {
        k_pass_a<<<dim3(NVT, 8), 256, 0, stream>>>(
            (const __bf16*)hcat_u, (const __bf16*)h2oT_u, S);
        k_pass_b<<<dim3(NVT, 8), 256, 0, stream>>>(
            (const __bf16*)hcat_u, (const __bf16*)h2oT_u, S, out);
    }
}

// Round 22
// 150.328 us; speedup vs baseline: 1.8674x; 1.6124x over previous
//
#include <hip/hip_runtime.h>

// Problem constants
#define V_SZ 32000
#define E_SZ 128
#define H_SZ 32
#define L_SZ 64
#define B_SZ 32
#define M_TOT 2048   // L*B rows
#define K2 64        // 2H
#define NVT 125      // V/256 col-slices

typedef __bf16 bf16x8 __attribute__((ext_vector_type(8)));
typedef float f32x4 __attribute__((ext_vector_type(4)));

__device__ __forceinline__ unsigned short f2bf(float f) {
    unsigned int u = __float_as_uint(f);
    u += 0x7FFFu + ((u >> 16) & 1u);   // round-to-nearest-even
    return (unsigned short)(u >> 16);
}

// ---------------------------------------------------------------------------
// Swapped-operand fragments (R12-R15 proven): vocab-as-M, hcat-rows-as-N.
// D: vocab = vbase + i*16 + lg*4 + reg, hrow = rowbase + j*16 + lr
// -> each lane's reg quad = 4 consecutive vocab of one output row.
// ---------------------------------------------------------------------------
__device__ __forceinline__ void load_vfrag(
    const __bf16* __restrict__ h2oT, int vbase, int lg, int lr,
    bf16x8 vf[4][2]) {
#pragma unroll
    for (int i = 0; i < 4; ++i) {
        const __bf16* vp = h2oT + (size_t)(vbase + i * 16 + lr) * K2 + lg * 8;
        vf[i][0] = *(const bf16x8*)(vp);
        vf[i][1] = *(const bf16x8*)(vp + 32);
    }
}

__device__ __forceinline__ void load_hfrag(
    const __bf16* __restrict__ hcat, int rowbase, int lg, int lr,
    bf16x8 hf[4][2]) {
#pragma unroll
    for (int j = 0; j < 4; ++j) {
        const __bf16* hp = hcat + (size_t)(rowbase + j * 16 + lr) * K2 + lg * 8;
        hf[j][0] = *(const bf16x8*)(hp);
        hf[j][1] = *(const bf16x8*)(hp + 32);
    }
}

// Full-ILP tile GEMM (R15-proven): 16 independent accumulators, 32 MFMAs.
__device__ __forceinline__ void tile_gemm_t(
    const bf16x8 vf[4][2], const bf16x8 hf[4][2], f32x4 acc[4][4]) {
#pragma unroll
    for (int i = 0; i < 4; ++i)
#pragma unroll
        for (int j = 0; j < 4; ++j) acc[i][j] = (f32x4){0.f, 0.f, 0.f, 0.f};
#pragma unroll
    for (int i = 0; i < 4; ++i)
#pragma unroll
        for (int j = 0; j < 4; ++j) {
            acc[i][j] = __builtin_amdgcn_mfma_f32_16x16x32_bf16(vf[i][0], hf[j][0], acc[i][j], 0, 0, 0);
            acc[i][j] = __builtin_amdgcn_mfma_f32_16x16x32_bf16(vf[i][1], hf[j][1], acc[i][j], 0, 0, 0);
        }
}

// 8-tile sweep with rolling double-buffered hfrag (R13/R14-proven pipeline,
// fully unrolled -> static buffer indexing).
template <typename EP>
__device__ __forceinline__ void sweep8(
    const __bf16* __restrict__ hcat, int y0, int lg, int lr, EP&& ep) {
    bf16x8 hfA[4][2], hfB[4][2];
    load_hfrag(hcat, y0, lg, lr, hfA);
#pragma unroll
    for (int t = 0; t < 8; ++t) {
        if (t & 1) {
            if (t < 7) load_hfrag(hcat, y0 + (t + 1) * 64, lg, lr, hfA);
            ep(hfB, y0 + t * 64);
        } else {
            if (t < 7) load_hfrag(hcat, y0 + (t + 1) * 64, lg, lr, hfB);
            ep(hfA, y0 + t * 64);
        }
    }
}

// Phase-A epilogue (R15-proven): sum-exp + 2-shfl reduce + atomicAdd -> S.
struct EpA {
    const bf16x8 (*vf)[2];
    float* S;
    int lane;
    __device__ __forceinline__ void operator()(const bf16x8 hf[4][2], int rowbase) const {
        f32x4 acc[4][4];
        tile_gemm_t((const bf16x8(*)[2])vf, hf, acc);
        float srow[4];
#pragma unroll
        for (int j = 0; j < 4; ++j) {
            float s = 0.f;
#pragma unroll
            for (int i = 0; i < 4; ++i)
#pragma unroll
                for (int r = 0; r < 4; ++r) s += __expf(acc[i][j][r]);
            srow[j] = s;
        }
#pragma unroll
        for (int j = 0; j < 4; ++j) {
            srow[j] += __shfl_xor(srow[j], 16, 64);
            srow[j] += __shfl_xor(srow[j], 32, 64);
        }
        if (lane < 16) {
#pragma unroll
            for (int j = 0; j < 4; ++j)
                atomicAdd(&S[rowbase + j * 16 + lane], srow[j]);
        }
    }
};

// Phase-B epilogue (R15-proven): lse = logf(S), recompute, direct f32x4 stores.
struct EpB {
    const bf16x8 (*vf)[2];
    const float* S;
    float* out;
    int vbase, lg, lr;
    __device__ __forceinline__ void operator()(const bf16x8 hf[4][2], int rowbase) const {
        float lsev[4];
#pragma unroll
        for (int j = 0; j < 4; ++j)
            lsev[j] = logf(S[rowbase + j * 16 + lr]);
        f32x4 acc[4][4];
        tile_gemm_t((const bf16x8(*)[2])vf, hf, acc);
#pragma unroll
        for (int j = 0; j < 4; ++j) {
            float* rp = out + (size_t)(rowbase + j * 16 + lr) * V_SZ + vbase + lg * 4;
#pragma unroll
            for (int i = 0; i < 4; ++i) {
                f32x4 v;
                v.x = acc[i][j].x - lsev[j];
                v.y = acc[i][j].y - lsev[j];
                v.z = acc[i][j].z - lsev[j];
                v.w = acc[i][j].w - lsev[j];
                *(f32x4*)(rp + i * 16) = v;
            }
        }
    }
};

// ---------------------------------------------------------------------------
// Kernel 1: blocks 0..499  -> transpose+convert h2o -> h2oT (64 rows each);
//           block 0 also zeroes S.  blocks 500..531 -> emb-GEMM + RNN.
// (R15-proven)
// ---------------------------------------------------------------------------
__global__ __launch_bounds__(256) void k_prep_rnn(
    const int* __restrict__ inp, const float* __restrict__ we,
    const float* __restrict__ i2h1, const float* __restrict__ i2h2,
    const float* __restrict__ h2o, const float* __restrict__ bias,
    const float* __restrict__ hinit,
    unsigned short* __restrict__ hcat_u, unsigned short* __restrict__ h2oT_u,
    float* __restrict__ S) {
    const int tid = threadIdx.x;
    const int p = blockIdx.x;
    if (p < 500) {
        if (p == 0) {
#pragma unroll
            for (int i = tid; i < M_TOT; i += 256) S[i] = 0.f;
        }
        const int v = p * 64 + (tid & 63);         // [0,32000) exact
        const int kg = tid >> 6;                   // 0..3
        unsigned int* dst = (unsigned int*)(h2oT_u + (size_t)v * K2 + kg * 16);
#pragma unroll
        for (int kk = 0; kk < 16; kk += 2) {
            const int k = kg * 16 + kk;
            float a = h2o[(size_t)k * V_SZ + v];
            float b = h2o[(size_t)(k + 1) * V_SZ + v];
            dst[kk >> 1] = (unsigned int)f2bf(a) | ((unsigned int)f2bf(b) << 16);
        }
        return;
    }
    // ---- emb + RNN block (one direction, 2 batch rows) ----
    const int w2 = p - 500;                        // 0..31
    const int dir = w2 >> 4;
    const int bpair = w2 & 15;
    const float* W = dir ? i2h2 : i2h1;
    __shared__ float Xl[L_SZ * 2 * H_SZ];          // 16 KB: X[t][bb][j]
    {
        const int j = tid & 31, bb = (tid >> 5) & 1, to = tid >> 6;
        const int b = bpair * 2 + bb;
        const float bj = bias[j];
        for (int tt = 0; tt < 16; ++tt) {
            const int t = to * 16 + tt;
            const int idx = inp[t * B_SZ + b];
            const float* er = we + (size_t)idx * E_SZ;
            float acc = bj;
#pragma unroll
            for (int k0 = 0; k0 < E_SZ; k0 += 4) {
                f32x4 e4 = *(const f32x4*)(er + k0);
                acc += e4.x * W[(k0 + 0) * H_SZ + j];
                acc += e4.y * W[(k0 + 1) * H_SZ + j];
                acc += e4.z * W[(k0 + 2) * H_SZ + j];
                acc += e4.w * W[(k0 + 3) * H_SZ + j];
            }
            Xl[(t * 2 + bb) * H_SZ + j] = acc;
        }
    }
    __syncthreads();
    if (tid < 64) {
        const int lane = tid;
        const int bb = lane >> 5;
        const int b = bpair * 2 + bb;
        const int j = lane & 31;
        const int srcbase = lane & 32;
        float wh[H_SZ];
#pragma unroll
        for (int k = 0; k < H_SZ; ++k) wh[k] = W[(E_SZ + k) * H_SZ + j];
        float h = hinit[j];
        for (int step = 0; step < L_SZ; ++step) {
            const int tt = dir ? (L_SZ - 1 - step) : step;
            hcat_u[(tt * B_SZ + b) * K2 + dir * H_SZ + j] = f2bf(h);
            float a0 = Xl[(tt * 2 + bb) * H_SZ + j];
            float a1 = 0.f, a2 = 0.f, a3 = 0.f;
#pragma unroll
            for (int k = 0; k < H_SZ; k += 4) {
                a0 += __shfl(h, srcbase | k, 64) * wh[k];
                a1 += __shfl(h, srcbase | (k + 1), 64) * wh[k + 1];
                a2 += __shfl(h, srcbase | (k + 2), 64) * wh[k + 2];
                a3 += __shfl(h, srcbase | (k + 3), 64) * wh[k + 3];
            }
            float x2 = (a0 + a1) + (a2 + a3);
            float e = __expf(2.f * x2);            // tanh = 1 - 2/(e^{2x}+1)
            h = 1.f - 2.f * __builtin_amdgcn_rcpf(e + 1.f);
        }
    }
}

// ---------------------------------------------------------------------------
// Kernel 2 (pass A): grid (125,4), 8 row-tiles/block, zero LDS/barriers.
// vfrag loaded once; hfrag rolling double-buffer; atomic partials -> S.
// ---------------------------------------------------------------------------
__global__ __launch_bounds__(256) void k_pass_a(
    const __bf16* __restrict__ hcat, const __bf16* __restrict__ h2oT,
    float* __restrict__ S) {
    const int tid = threadIdx.x;
    const int wave = tid >> 6, lane = tid & 63;
    const int lg = lane >> 4, lr = lane & 15;
    const int y0 = blockIdx.y * 512;               // 8 tiles x 64 rows
    const int vbase = blockIdx.x * 256 + wave * 64;
    bf16x8 vf[4][2];
    load_vfrag(h2oT, vbase, lg, lr, vf);
    EpA epa{vf, S, lane};
    sweep8(hcat, y0, lg, lr, epa);
}

// ---------------------------------------------------------------------------
// Kernel 3 (pass B): grid (125,4), 8 row-tiles/block, zero LDS/barriers.
// lse = logf(S[row]) inline; direct f32x4 stores from accumulators.
// ---------------------------------------------------------------------------
__global__ __launch_bounds__(256) void k_pass_b(
    const __bf16* __restrict__ hcat, const __bf16* __restrict__ h2oT,
    const float* __restrict__ S, float* __restrict__ out) {
    const int tid = threadIdx.x;
    const int wave = tid >> 6, lane = tid & 63;
    const int lg = lane >> 4, lr = lane & 15;
    const int y0 = blockIdx.y * 512;               // 8 tiles x 64 rows
    const int vbase = blockIdx.x * 256 + wave * 64;
    bf16x8 vf[4][2];
    load_vfrag(h2oT, vbase, lg, lr, vf);
    EpB epb{vf, S, out, vbase, lg, lr};
    sweep8(hcat, y0, lg, lr, epb);
}

// ---------------------------------------------------------------------------
extern "C" void kernel_launch(void* const* d_in, const int* in_sizes, int n_in,
                              void* d_out, int out_size, void* d_ws, size_t ws_size,
                              hipStream_t stream) {
    (void)in_sizes; (void)n_in; (void)out_size; (void)ws_size;
    const int*   inp   = (const int*)d_in[0];
    const float* we    = (const float*)d_in[1];
    const float* i2h1  = (const float*)d_in[2];
    const float* i2h2  = (const float*)d_in[3];
    const float* h2o   = (const float*)d_in[4];
    const float* bias  = (const float*)d_in[5];
    const float* hinit = (const float*)d_in[6];
    float* out = (float*)d_out;
    char* ws = (char*)d_ws;
    unsigned short* hcat_u = (unsigned short*)(ws);           //  262144 B
    unsigned short* h2oT_u = (unsigned short*)(ws + 262144);  // 4096000 B
    float*          S      = (float*)(ws + 4358144);          //    8192 B

    k_prep_rnn<<<532, 256, 0, stream>>>(inp, we, i2h1, i2h2, h2o, bias, hinit,
                                        hcat_u, h2oT_u, S);
    k_pass_a<<<dim3(NVT, 4), 256, 0, stream>>>(
        (const __bf16*)hcat_u, (const __bf16*)h2oT_u, S);
    k_pass_b<<<dim3(NVT, 4), 256, 0, stream>>>(
        (const __bf16*)hcat_u, (const __bf16*)h2oT_u, S, out);
}